// Round 10
// baseline (1304.658 us; speedup 1.0000x reference)
//
#include <hip/hip_runtime.h>

#define LAMF 0.1f
#define LRF  0.01f
#define B1F  0.9f
#define B2F  0.99f
#define EPSF 1e-8f

constexpr int NB = 32;
constexpr int PLANE = 61 * 61;            // 3721
constexpr int USZ = NB * 64 * PLANE;      // u f32 elements
constexpr int ACSZ = NB * 62 * 68 * 64;   // act NHWC-padded f16 elements
constexpr int ERP = 264;                  // e-patch LDS row stride (f16): 256+8

// NOTE (measured R5/R6): __launch_bounds__ 2nd arg acts as min BLOCKS/CU here;
// VGPR cap = 131072/(threads*arg2). (512,6) gave 40 VGPR and a 4x spill
// regression. -> No 2nd arg anywhere in this file.

typedef _Float16 f16;
typedef __attribute__((ext_vector_type(8))) _Float16 f16x8;
typedef f16x8 f16x8u __attribute__((aligned(8)));    // 8B-aligned 16B load
typedef __attribute__((ext_vector_type(4))) _Float16 f16x4;  // 8B aligned
typedef __attribute__((ext_vector_type(4))) float f32x4;
typedef f32x4 f32x4u __attribute__((aligned(4)));    // 4B-aligned 16B ld/st

// ---------------------------------------------------------------------------
// prep: filter into exact MFMA fragment order (f16).  (unchanged from R8/R9)
//  F2f: [ks 0..31][lane][e]  k = tap*64+c ; tap=(ii,kk), n=(s,r)=lane&15
//  Bf : [ks 0..7][nt 0..3][lane][e]  k = kh*16+kw ; n = c
// ---------------------------------------------------------------------------
__global__ __launch_bounds__(256) void prep(const float* __restrict__ filt,
                                            f16* __restrict__ F2f,
                                            f16* __restrict__ Bf) {
    int o = blockIdx.x * 256 + threadIdx.x;       // 32768 threads
    if (o < 16384) {
        int e = o & 7, lane = (o >> 3) & 63, ks = o >> 9;
        int nn = lane & 15, kg = lane >> 4;
        int tap = ks >> 1, ii = tap >> 2, kk = tap & 3;
        int c = (ks & 1) * 32 + kg * 8 + e;
        int s = nn >> 2, r = nn & 3;
        F2f[o] = (f16)filt[((4 * (3 - ii) + s) * 16 + (4 * (3 - kk) + r)) * 64 + c];
    } else {
        int o2 = o - 16384;
        int e = o2 & 7, lane = (o2 >> 3) & 63;
        int nt = (o2 >> 9) & 3, ks = o2 >> 11;
        int k = ks * 32 + (lane >> 4) * 8 + e;
        int c = nt * 16 + (lane & 15);
        Bf[o2] = (f16)filt[k * 64 + c];
    }
}

// ---------------------------------------------------------------------------
// step (fused ek+gk): per block (b,i):
//  Phase R (MODE!=0): wave w computes recon row-band p=i+w (all 64 q, 4 MFMA
//   tiles, K=1024) via SWAPPED mfma(F,A): D col=q, D rows=n=(s,r) -> thread's
//   4 regs = 4 consecutive x = one ds_write_b64 into e-patch LDS [16][ERP].
//   (MODE 0: act=0 -> e-patch = (f16)img directly.)
//  Phase PV: R9's gk GEMM (M=j, N=64c, K=256 taps) reading A-frags from the
//   e-patch LDS, B from Bf staged over the F2f LDS region; fused Adam
//   epilogue (u f32, m/v packed f16 pairs).  MODE 2 writes only NHWC out.
// ---------------------------------------------------------------------------
template <int MODE>
__global__ __launch_bounds__(256) void step(float* __restrict__ u,
                                            f16* __restrict__ mv,
                                            f16* __restrict__ actc,
                                            float* __restrict__ out,
                                            const float* __restrict__ img,
                                            const f16* __restrict__ F2f,
                                            const f16* __restrict__ Bf,
                                            float rbc1, float rbc2) {
    __shared__ __align__(16) f16 FS[16384];       // F2f, then re-staged as Bf
    __shared__ __align__(16) f16 EL[17 * ERP];    // e-patch + guard row
    int tid  = threadIdx.x;
    int bid  = blockIdx.x;                        // 1952 = 8 * 244
    int n    = (bid & 7) * 244 + (bid >> 3);
    int b    = n / 61;
    int i    = n % 61;
    int wave = __builtin_amdgcn_readfirstlane(tid >> 6);
    int lane = tid & 63;
    int ml   = lane & 15;
    int kg   = lane >> 4;

    if (MODE != 0) {
        {   // stage F2f
            const f32x4* s = (const f32x4*)F2f;
            f32x4* d = (f32x4*)FS;
            for (int idx = tid; idx < 2048; idx += 256) d[idx] = s[idx];
        }
        __syncthreads();

        int p = i + wave;                         // <= 63; recon rows 4p..4p+3
        const f16* rowp[4];
#pragma unroll
        for (int ii = 0; ii < 4; ++ii) {
            int row = p - 3 + ii;
            if (row < 0 || row > 60) row = 61;    // permanent zero row
            rowp[ii] = actc + (size_t)(b * 62 + row) * (68 * 64);
        }

        f32x4 acc[4] = {{0.f,0.f,0.f,0.f}, {0.f,0.f,0.f,0.f},
                        {0.f,0.f,0.f,0.f}, {0.f,0.f,0.f,0.f}};
#pragma unroll
        for (int ks = 0; ks < 32; ++ks) {
            int tap = ks >> 1, ii = tap >> 2, kk = tap & 3;
            int c0  = (ks & 1) * 32 + kg * 8;
            f16x8 F = *(const f16x8*)(FS + (ks * 64 + lane) * 8);
            const f16* base = rowp[ii] + (kk + 1) * 64 + c0;   // slot = q+1+kk
#pragma unroll
            for (int qt = 0; qt < 4; ++qt) {
                f16x8 A = *(const f16x8u*)(base + (qt * 16 + ml) * 64);
                acc[qt] = __builtin_amdgcn_mfma_f32_16x16x32_f16(F, A, acc[qt],
                                                                 0, 0, 0);
            }
        }

        // D (swapped): col=lane&15=q-in-tile ; row=(lane>>4)*4+rg = n=(s,r)
        //  -> s = kg, r = rg : thread's 4 regs are x = 4q..4q+3 consecutive.
        const float* ibase = img + ((size_t)b * 256 + 4 * p + kg) * 256;
        f16* erow = EL + (4 * wave + kg) * ERP;
#pragma unroll
        for (int qt = 0; qt < 4; ++qt) {
            int q = qt * 16 + ml;
            f32x4 iv = *(const f32x4*)(ibase + 4 * q);
            f16x4 ev = {(f16)(iv[0] - acc[qt][0]), (f16)(iv[1] - acc[qt][1]),
                        (f16)(iv[2] - acc[qt][2]), (f16)(iv[3] - acc[qt][3])};
            *(f16x4*)(erow + 4 * q) = ev;
        }
    } else {
        // MODE 0: u=0 -> act=0 -> e = img
        const float* ib = img + ((size_t)b * 256 + 4 * i) * 256;
        for (int idx = tid; idx < 16 * 64; idx += 256) {
            int row = idx >> 6, cq = idx & 63;
            f32x4 iv = *(const f32x4*)(ib + row * 256 + 4 * cq);
            f16x4 ev = {(f16)iv[0], (f16)iv[1], (f16)iv[2], (f16)iv[3]};
            *(f16x4*)(EL + row * ERP + 4 * cq) = ev;
        }
    }
    __syncthreads();
    {   // stage Bf over the F2f region (recon done with it)
        const f32x4* s = (const f32x4*)Bf;
        f32x4* d = (f32x4*)FS;
        for (int idx = tid; idx < 2048; idx += 256) d[idx] = s[idx];
    }
    __syncthreads();

    // ---- PV GEMM (R9 gk, A from EL) ----
    int jt  = wave;
    const f16* ebase = EL + 4 * (jt * 16 + ml) + (kg & 1) * 8;
    int khb = kg >> 1;
    f32x4 acc2[4] = {{0.f,0.f,0.f,0.f}, {0.f,0.f,0.f,0.f},
                     {0.f,0.f,0.f,0.f}, {0.f,0.f,0.f,0.f}};
#pragma unroll
    for (int ks = 0; ks < 8; ++ks) {
        f16x8 A = *(const f16x8u*)(ebase + (2 * ks + khb) * ERP);
#pragma unroll
        for (int nt = 0; nt < 4; ++nt) {
            f16x8 B = *(const f16x8*)(FS + ((ks * 4 + nt) * 64 + lane) * 8);
            acc2[nt] = __builtin_amdgcn_mfma_f32_16x16x32_f16(A, B, acc2[nt],
                                                              0, 0, 0);
        }
    }

    // ---- fused Adam epilogue (identical to R9) ----
    int j0 = jt * 16 + (lane >> 4) * 4;           // <= 60; j0+3 may reach 63
    bool full = (j0 <= 56);
#pragma unroll
    for (int nt = 0; nt < 4; ++nt) {
        int cc = nt * 16 + (lane & 15);
        size_t sbase = (size_t)(b * 64 + cc) * PLANE + (size_t)i * 61 + j0;
        if (MODE == 0) {
            f32x4 u4;
            f16x8 mv8;
#pragma unroll
            for (int rg = 0; rg < 4; ++rg) {
                float g  = acc2[nt][rg];
                float m2 = (1.f - B1F) * g;
                float v2 = (1.f - B2F) * g * g;
                u4[rg] = LRF * (m2 * rbc1) / (sqrtf(v2 * rbc2) + EPSF);
                mv8[2 * rg]     = (f16)m2;
                mv8[2 * rg + 1] = (f16)v2;
            }
            if (full) {
                *(f32x4u*)(u + sbase) = u4;
                *(f16x8u*)(mv + 2 * sbase) = mv8;
            } else {
                u[sbase] = u4[0];
                mv[2 * sbase] = mv8[0];
                mv[2 * sbase + 1] = mv8[1];
            }
            f16* ab = actc + ((size_t)(b * 62 + i) * 68 + (j0 + 4)) * 64 + cc;
#pragma unroll
            for (int rg = 0; rg < 4; ++rg)
                if (j0 + rg <= 60) ab[rg * 64] = (f16)fmaxf(u4[rg] - LAMF, 0.f);
        } else {
            f32x4 uu;
            f16x8 mv8;
            if (full) {
                uu  = *(const f32x4u*)(u + sbase);
                mv8 = *(const f16x8u*)(mv + 2 * sbase);
            } else {
                uu[0] = u[sbase]; uu[1] = uu[2] = uu[3] = 0.f;
                mv8[0] = mv[2 * sbase]; mv8[1] = mv[2 * sbase + 1];
            }
            float un[4];
#pragma unroll
            for (int rg = 0; rg < 4; ++rg) {
                float a  = fmaxf(uu[rg] - LAMF, 0.f);
                float g  = acc2[nt][rg] + a - uu[rg];
                float m2 = B1F * (float)mv8[2 * rg]     + (1.f - B1F) * g;
                float v2 = B2F * (float)mv8[2 * rg + 1] + (1.f - B2F) * g * g;
                mv8[2 * rg]     = (f16)m2;
                mv8[2 * rg + 1] = (f16)v2;
                un[rg] = uu[rg] + LRF * (m2 * rbc1) / (sqrtf(v2 * rbc2) + EPSF);
            }
            if (MODE == 1) {
                if (full) {
                    f32x4 u4 = {un[0], un[1], un[2], un[3]};
                    *(f32x4u*)(u + sbase) = u4;
                    *(f16x8u*)(mv + 2 * sbase) = mv8;
                } else {
                    u[sbase] = un[0];
                    mv[2 * sbase] = mv8[0];
                    mv[2 * sbase + 1] = mv8[1];
                }
                f16* ab = actc + ((size_t)(b * 62 + i) * 68 + (j0 + 4)) * 64 + cc;
#pragma unroll
                for (int rg = 0; rg < 4; ++rg)
                    if (j0 + rg <= 60) ab[rg * 64] = (f16)fmaxf(un[rg] - LAMF, 0.f);
            } else {                              // MODE 2: output only
                float* ob = out + (((size_t)b * 61 + i) * 61 + j0) * 64 + cc;
#pragma unroll
                for (int rg = 0; rg < 4; ++rg)
                    if (j0 + rg <= 60) ob[rg * 64] = fmaxf(un[rg] - LAMF, 0.f);
            }
        }
    }
}

// ---------------------------------------------------------------------------
extern "C" void kernel_launch(void* const* d_in, const int* in_sizes, int n_in,
                              void* d_out, int out_size, void* d_ws, size_t ws_size,
                              hipStream_t stream) {
    const float* img  = (const float*)d_in[0];
    const float* filt = (const float*)d_in[1];
    float* out = (float*)d_out;

    float* u  = (float*)d_ws;
    f16* mv   = (f16*)(u + USZ);      // 2*USZ f16 interleaved (m,v)
    f16* actc = mv + 2 * (size_t)USZ;
    f16* F2f  = actc + ACSZ;
    f16* Bf   = F2f + 16384;

    hipMemsetAsync(actc, 0, (size_t)ACSZ * sizeof(f16), stream);
    prep<<<128, 256, 0, stream>>>(filt, F2f, Bf);

    float b1p = B1F, b2p = B2F;
    step<0><<<1952, 256, 0, stream>>>(u, mv, actc, out, img, F2f, Bf,
                                      1.f / (1.f - b1p), 1.f / (1.f - b2p));
    for (int t = 1; t < 9; ++t) {
        b1p *= B1F;
        b2p *= B2F;
        step<1><<<1952, 256, 0, stream>>>(u, mv, actc, out, img, F2f, Bf,
                                          1.f / (1.f - b1p), 1.f / (1.f - b2p));
    }
    b1p *= B1F;
    b2p *= B2F;
    step<2><<<1952, 256, 0, stream>>>(u, mv, actc, out, img, F2f, Bf,
                                      1.f / (1.f - b1p), 1.f / (1.f - b2p));
}

// Round 11
// 446.789 us; speedup vs baseline: 2.9201x; 2.9201x over previous
//
#include <hip/hip_runtime.h>

#define LAMF 0.1f
#define LRF  0.01f
#define B1F  0.9f
#define B2F  0.99f
#define EPSF 1e-8f

constexpr int NB = 32;
constexpr int PLANE = 61 * 61;            // 3721
constexpr int USZ = NB * 64 * PLANE;      // u f32 elements
constexpr int ESZ = NB * 256 * 256;       // e f16 elements
constexpr int ACSZ = NB * 62 * 68 * 64;   // act NHWC-padded f16 elements

// NOTE (measured R5/R6): __launch_bounds__ 2nd arg acts as min BLOCKS/CU here;
// VGPR cap = 131072/(threads*arg2). -> single-arg launch_bounds only.
// NOTE (measured R10): fusing recon into the per-(b,i) step kernel = 4 GB of
// scattered L2 reads (MfmaUtil 5.6%, all pipes idle) -> keep two kernels.

typedef _Float16 f16;
typedef __attribute__((ext_vector_type(8))) _Float16 f16x8;
typedef f16x8 f16x8u __attribute__((aligned(8)));
typedef __attribute__((ext_vector_type(4))) _Float16 f16x4;
typedef __attribute__((ext_vector_type(4))) float f32x4;
typedef f32x4 f32x4u __attribute__((aligned(4)));

// ---------------------------------------------------------------------------
// prep: filter into exact MFMA fragment order (f16).  (unchanged from R8/R9)
//  F2f: [ks 0..31][lane][e]  k = tap*64+c ; tap=(ii,kk), n=(s,r)=lane&15
//  Bf : [ks 0..7][nt 0..3][lane][e]  k = kh*16+kw ; n = c
// ---------------------------------------------------------------------------
__global__ __launch_bounds__(256) void prep(const float* __restrict__ filt,
                                            f16* __restrict__ F2f,
                                            f16* __restrict__ Bf) {
    int o = blockIdx.x * 256 + threadIdx.x;       // 32768 threads
    if (o < 16384) {
        int e = o & 7, lane = (o >> 3) & 63, ks = o >> 9;
        int nn = lane & 15, kg = lane >> 4;
        int tap = ks >> 1, ii = tap >> 2, kk = tap & 3;
        int c = (ks & 1) * 32 + kg * 8 + e;
        int s = nn >> 2, r = nn & 3;
        F2f[o] = (f16)filt[((4 * (3 - ii) + s) * 16 + (4 * (3 - kk) + r)) * 64 + c];
    } else {
        int o2 = o - 16384;
        int e = o2 & 7, lane = (o2 >> 3) & 63;
        int nt = (o2 >> 9) & 3, ks = o2 >> 11;
        int k = ks * 32 + (lane >> 4) * 8 + e;
        int c = nt * 16 + (lane & 15);
        Bf[o2] = (f16)filt[k * 64 + c];
    }
}

// eh = (f16)img   (t=0: act=0 -> e = img)
__global__ __launch_bounds__(256) void cvt(const float* __restrict__ img,
                                           f16* __restrict__ eh) {
    int o = blockIdx.x * 256 + threadIdx.x;       // ESZ/4 threads
    f32x4 v = ((const f32x4*)img)[o];
    f16x4 h = {(f16)v[0], (f16)v[1], (f16)v[2], (f16)v[3]};
    *(f16x4*)(eh + (size_t)o * 4) = h;
}

// ---------------------------------------------------------------------------
// ek v2: e = img - conv_T(act).  Block = (b, p-pair), 512 thr = 8 waves =
// (pp 0..1) x (qt 0..3).  Act halo rows 2pg-3..2pg+1 staged DENSE in LDS
// (43.5 KB) with XOR swizzle byte^=((slot&7)<<4) (write & read identically);
// A-frag = swizzled ds_read_b128, B-frag = staged F2f.  Swapped mfma(F,A):
// D col = q-in-tile (=ml), row = n=(s,r) (s=kg, r=reg) -> coalesced f16x4
// e-writes at y=4p+kg, x=4q..4q+3.  Each wave owns full K (no reduce).
// ---------------------------------------------------------------------------
__global__ __launch_bounds__(512) void ek(const f16* __restrict__ actc,
                                          const float* __restrict__ img,
                                          const f16* __restrict__ F2f,
                                          f16* __restrict__ eh) {
    __shared__ __align__(16) char AS[5 * 68 * 128];   // 43520 B act halo
    __shared__ __align__(16) f16 FS[16384];           // 32 KB F2f
    int tid = threadIdx.x;
    int bid = blockIdx.x;                         // 1024 = 8 XCD * 128
    int n   = (bid & 7) * 128 + (bid >> 3);
    int b   = n >> 5;
    int pg  = n & 31;

    {   // stage F2f
        const f32x4* s = (const f32x4*)F2f;
        f32x4* d = (f32x4*)FS;
        for (int idx = tid; idx < 2048; idx += 512) d[idx] = s[idx];
    }
    {   // stage act halo rows 2pg-3 .. 2pg+1 (OOB rows -> zeros), swizzled
        int base_row = 2 * pg - 3;
        const f16* actb = actc + (size_t)b * (62 * 68 * 64);
        for (int t = tid; t < 5 * 68 * 8; t += 512) {
            int rw   = t / (68 * 8);
            int rem  = t % (68 * 8);
            int slot = rem >> 3;
            int kgc  = rem & 7;
            int arow = base_row + rw;
            f16x8 v = {};
            if (arow >= 0 && arow <= 60)
                v = *(const f16x8*)(actb + ((size_t)arow * 68 + slot) * 64 + kgc * 8);
            unsigned off = rw * 8704 + slot * 128 + ((kgc * 16) ^ ((slot & 7) << 4));
            *(f16x8*)(AS + off) = v;
        }
    }
    __syncthreads();

    int wave = __builtin_amdgcn_readfirstlane(tid >> 6);
    int pp   = wave >> 2;
    int qt   = wave & 3;
    int lane = tid & 63;
    int ml   = lane & 15;
    int kg   = lane >> 4;
    int q    = qt * 16 + ml;

    f32x4 acc = {0.f, 0.f, 0.f, 0.f};
#pragma unroll
    for (int ks = 0; ks < 32; ++ks) {
        int tap = ks >> 1, ii = tap >> 2, kk = tap & 3;
        int rw    = pp + ii;
        int chunk = (ks & 1) * 4 + kg;            // c0 = (ks&1)*32 + kg*8
        int slot  = q + 1 + kk;
        unsigned off = rw * 8704 + slot * 128 + ((chunk * 16) ^ ((slot & 7) << 4));
        f16x8 A = *(const f16x8*)(AS + off);
        f16x8 F = *(const f16x8*)(FS + (ks * 64 + lane) * 8);
        acc = __builtin_amdgcn_mfma_f32_16x16x32_f16(F, A, acc, 0, 0, 0);
    }

    // y = 4p + kg (s=kg), x = 4q + rg (r=rg): one coalesced f16x4 store
    int p = 2 * pg + pp;
    size_t rbase = ((size_t)b * 256 + 4 * p + kg) * 256;
    f32x4 iv = *(const f32x4*)(img + rbase + 4 * q);
    f16x4 ev = {(f16)(iv[0] - acc[0]), (f16)(iv[1] - acc[1]),
                (f16)(iv[2] - acc[2]), (f16)(iv[3] - acc[3])};
    *(f16x4*)(eh + rbase + 4 * q) = ev;
}

// ---------------------------------------------------------------------------
// gk (MFMA): conv(e,filt) + fused Adam.  GEMM M=(b,i,j) N=64c K=256.
// u fp32; m,v interleaved f16 pairs.  Identical to R9.
// ---------------------------------------------------------------------------
template <int MODE>
__global__ __launch_bounds__(256) void gk(float* __restrict__ u,
                                          f16* __restrict__ mv,
                                          f16* __restrict__ actc,
                                          float* __restrict__ out,
                                          const f16* __restrict__ eh,
                                          const f16* __restrict__ Bf,
                                          float rbc1, float rbc2) {
    __shared__ f16 BS[8 * 4 * 64 * 8];            // 16 KB
    int tid = threadIdx.x;
    {
        const f32x4* s = (const f32x4*)Bf;
        f32x4* d = (f32x4*)BS;
        for (int idx = tid; idx < 1024; idx += 256) d[idx] = s[idx];
    }
    __syncthreads();

    int bid = blockIdx.x;                         // 1952 = 8 * 244
    int n   = (bid & 7) * 244 + (bid >> 3);
    int b   = n / 61;
    int i   = n % 61;
    int jt  = __builtin_amdgcn_readfirstlane(tid >> 6);
    int lane = tid & 63;
    int kg  = lane >> 4;
    int ml  = lane & 15;

    const f16* ebase = eh + ((size_t)b * 256 + 4 * i) * 256
                     + 4 * (jt * 16 + ml) + (kg & 1) * 8;
    int khb = kg >> 1;

    f32x4 acc[4] = {{0.f,0.f,0.f,0.f}, {0.f,0.f,0.f,0.f},
                    {0.f,0.f,0.f,0.f}, {0.f,0.f,0.f,0.f}};
#pragma unroll
    for (int ks = 0; ks < 8; ++ks) {
        f16x8 A = *(const f16x8u*)(ebase + (2 * ks + khb) * 256);
#pragma unroll
        for (int nt = 0; nt < 4; ++nt) {
            f16x8 B = *(const f16x8*)(BS + ((ks * 4 + nt) * 64 + lane) * 8);
            acc[nt] = __builtin_amdgcn_mfma_f32_16x16x32_f16(A, B, acc[nt], 0, 0, 0);
        }
    }

    int j0 = jt * 16 + (lane >> 4) * 4;
    bool full = (j0 <= 56);
#pragma unroll
    for (int nt = 0; nt < 4; ++nt) {
        int cc = nt * 16 + (lane & 15);
        size_t sbase = (size_t)(b * 64 + cc) * PLANE + (size_t)i * 61 + j0;
        if (MODE == 0) {
            f32x4 u4;
            f16x8 mv8;
#pragma unroll
            for (int rg = 0; rg < 4; ++rg) {
                float g  = acc[nt][rg];
                float m2 = (1.f - B1F) * g;
                float v2 = (1.f - B2F) * g * g;
                u4[rg] = LRF * (m2 * rbc1) / (sqrtf(v2 * rbc2) + EPSF);
                mv8[2 * rg]     = (f16)m2;
                mv8[2 * rg + 1] = (f16)v2;
            }
            if (full) {
                *(f32x4u*)(u + sbase) = u4;
                *(f16x8u*)(mv + 2 * sbase) = mv8;
            } else {
                u[sbase] = u4[0];
                mv[2 * sbase] = mv8[0];
                mv[2 * sbase + 1] = mv8[1];
            }
            f16* ab = actc + ((size_t)(b * 62 + i) * 68 + (j0 + 4)) * 64 + cc;
#pragma unroll
            for (int rg = 0; rg < 4; ++rg)
                if (j0 + rg <= 60) ab[rg * 64] = (f16)fmaxf(u4[rg] - LAMF, 0.f);
        } else {
            f32x4 uu;
            f16x8 mv8;
            if (full) {
                uu  = *(const f32x4u*)(u + sbase);
                mv8 = *(const f16x8u*)(mv + 2 * sbase);
            } else {
                uu[0] = u[sbase]; uu[1] = uu[2] = uu[3] = 0.f;
                mv8[0] = mv[2 * sbase]; mv8[1] = mv[2 * sbase + 1];
            }
            float un[4];
#pragma unroll
            for (int rg = 0; rg < 4; ++rg) {
                float a  = fmaxf(uu[rg] - LAMF, 0.f);
                float g  = acc[nt][rg] + a - uu[rg];
                float m2 = B1F * (float)mv8[2 * rg]     + (1.f - B1F) * g;
                float v2 = B2F * (float)mv8[2 * rg + 1] + (1.f - B2F) * g * g;
                mv8[2 * rg]     = (f16)m2;
                mv8[2 * rg + 1] = (f16)v2;
                un[rg] = uu[rg] + LRF * (m2 * rbc1) / (sqrtf(v2 * rbc2) + EPSF);
            }
            if (MODE == 1) {
                if (full) {
                    f32x4 u4 = {un[0], un[1], un[2], un[3]};
                    *(f32x4u*)(u + sbase) = u4;
                    *(f16x8u*)(mv + 2 * sbase) = mv8;
                } else {
                    u[sbase] = un[0];
                    mv[2 * sbase] = mv8[0];
                    mv[2 * sbase + 1] = mv8[1];
                }
                f16* ab = actc + ((size_t)(b * 62 + i) * 68 + (j0 + 4)) * 64 + cc;
#pragma unroll
                for (int rg = 0; rg < 4; ++rg)
                    if (j0 + rg <= 60) ab[rg * 64] = (f16)fmaxf(un[rg] - LAMF, 0.f);
            } else {                              // MODE 2: output only
                float* ob = out + (((size_t)b * 61 + i) * 61 + j0) * 64 + cc;
#pragma unroll
                for (int rg = 0; rg < 4; ++rg)
                    if (j0 + rg <= 60) ob[rg * 64] = fmaxf(un[rg] - LAMF, 0.f);
            }
        }
    }
}

// ---------------------------------------------------------------------------
extern "C" void kernel_launch(void* const* d_in, const int* in_sizes, int n_in,
                              void* d_out, int out_size, void* d_ws, size_t ws_size,
                              hipStream_t stream) {
    const float* img  = (const float*)d_in[0];
    const float* filt = (const float*)d_in[1];
    float* out = (float*)d_out;

    float* u  = (float*)d_ws;
    f16* mv   = (f16*)(u + USZ);      // 2*USZ f16 interleaved (m,v)
    f16* eh   = mv + 2 * (size_t)USZ;
    f16* actc = eh + ESZ;
    f16* F2f  = actc + ACSZ;
    f16* Bf   = F2f + 16384;

    hipMemsetAsync(actc, 0, (size_t)ACSZ * sizeof(f16), stream);
    prep<<<128, 256, 0, stream>>>(filt, F2f, Bf);
    cvt<<<ESZ / 1024, 256, 0, stream>>>(img, eh);

    float b1p = B1F, b2p = B2F;
    gk<0><<<1952, 256, 0, stream>>>(u, mv, actc, out, eh, Bf,
                                    1.f / (1.f - b1p), 1.f / (1.f - b2p));
    for (int t = 1; t < 9; ++t) {
        b1p *= B1F;
        b2p *= B2F;
        ek<<<1024, 512, 0, stream>>>(actc, img, F2f, eh);
        gk<1><<<1952, 256, 0, stream>>>(u, mv, actc, out, eh, Bf,
                                        1.f / (1.f - b1p), 1.f / (1.f - b2p));
    }
    b1p *= B1F;
    b2p *= B2F;
    ek<<<1024, 512, 0, stream>>>(actc, img, F2f, eh);
    gk<2><<<1952, 256, 0, stream>>>(u, mv, actc, out, eh, Bf,
                                    1.f / (1.f - b1p), 1.f / (1.f - b2p));
}

// Round 12
// 431.121 us; speedup vs baseline: 3.0262x; 1.0363x over previous
//
#include <hip/hip_runtime.h>

#define LAMF 0.1f
#define LRF  0.01f
#define B1F  0.9f
#define B2F  0.99f
#define EPSF 1e-8f

constexpr int NB = 32;
constexpr int PLANE = 61 * 61;            // 3721
constexpr int USZ = NB * 64 * PLANE;      // u f32 elements (NHWC [b][i][j][c])
constexpr int ESZ = NB * 256 * 256;       // e f16 elements
constexpr int ACSZ = NB * 62 * 68 * 64;   // act NHWC-padded f16 elements

// NOTE (measured R5/R6): __launch_bounds__ 2nd arg acts as min BLOCKS/CU here;
// VGPR cap = 131072/(threads*arg2). -> single-arg launch_bounds only.
// NOTE (measured R10): fusing recon into the per-(b,i) step kernel = 4 GB of
// scattered L2 reads -> keep two kernels.
// NOTE (R12): gk uses SWAPPED mfma(B,A) -> D rows = c, cols = j; u/mv NHWC ->
// all state accesses 16B-contiguous per lane (was 64B segments 14.9KB apart).

typedef _Float16 f16;
typedef __attribute__((ext_vector_type(8))) _Float16 f16x8;
typedef f16x8 f16x8u __attribute__((aligned(8)));
typedef __attribute__((ext_vector_type(4))) _Float16 f16x4;
typedef __attribute__((ext_vector_type(4))) float f32x4;
typedef f32x4 f32x4u __attribute__((aligned(4)));

// ---------------------------------------------------------------------------
// prep: filter into exact MFMA fragment order (f16).  (unchanged from R8/R9)
//  F2f: [ks 0..31][lane][e]  k = tap*64+c ; tap=(ii,kk), n=(s,r)=lane&15
//  Bf : [ks 0..7][nt 0..3][lane][e]  k = kh*16+kw ; n = c
// ---------------------------------------------------------------------------
__global__ __launch_bounds__(256) void prep(const float* __restrict__ filt,
                                            f16* __restrict__ F2f,
                                            f16* __restrict__ Bf) {
    int o = blockIdx.x * 256 + threadIdx.x;       // 32768 threads
    if (o < 16384) {
        int e = o & 7, lane = (o >> 3) & 63, ks = o >> 9;
        int nn = lane & 15, kg = lane >> 4;
        int tap = ks >> 1, ii = tap >> 2, kk = tap & 3;
        int c = (ks & 1) * 32 + kg * 8 + e;
        int s = nn >> 2, r = nn & 3;
        F2f[o] = (f16)filt[((4 * (3 - ii) + s) * 16 + (4 * (3 - kk) + r)) * 64 + c];
    } else {
        int o2 = o - 16384;
        int e = o2 & 7, lane = (o2 >> 3) & 63;
        int nt = (o2 >> 9) & 3, ks = o2 >> 11;
        int k = ks * 32 + (lane >> 4) * 8 + e;
        int c = nt * 16 + (lane & 15);
        Bf[o2] = (f16)filt[k * 64 + c];
    }
}

// eh = (f16)img   (t=0: act=0 -> e = img)
__global__ __launch_bounds__(256) void cvt(const float* __restrict__ img,
                                           f16* __restrict__ eh) {
    int o = blockIdx.x * 256 + threadIdx.x;       // ESZ/4 threads
    f32x4 v = ((const f32x4*)img)[o];
    f16x4 h = {(f16)v[0], (f16)v[1], (f16)v[2], (f16)v[3]};
    *(f16x4*)(eh + (size_t)o * 4) = h;
}

// ---------------------------------------------------------------------------
// ek v2 (unchanged from R11): e = img - conv_T(act).  Block = (b, p-pair),
// 512 thr = 8 waves = (pp x qt).  Act halo staged dense in LDS with XOR
// swizzle; swapped mfma(F,A) -> coalesced f16x4 e-writes.
// ---------------------------------------------------------------------------
__global__ __launch_bounds__(512) void ek(const f16* __restrict__ actc,
                                          const float* __restrict__ img,
                                          const f16* __restrict__ F2f,
                                          f16* __restrict__ eh) {
    __shared__ __align__(16) char AS[5 * 68 * 128];   // 43520 B act halo
    __shared__ __align__(16) f16 FS[16384];           // 32 KB F2f
    int tid = threadIdx.x;
    int bid = blockIdx.x;                         // 1024 = 8 XCD * 128
    int n   = (bid & 7) * 128 + (bid >> 3);
    int b   = n >> 5;
    int pg  = n & 31;

    {   // stage F2f
        const f32x4* s = (const f32x4*)F2f;
        f32x4* d = (f32x4*)FS;
        for (int idx = tid; idx < 2048; idx += 512) d[idx] = s[idx];
    }
    {   // stage act halo rows 2pg-3 .. 2pg+1 (OOB rows -> zeros), swizzled
        int base_row = 2 * pg - 3;
        const f16* actb = actc + (size_t)b * (62 * 68 * 64);
        for (int t = tid; t < 5 * 68 * 8; t += 512) {
            int rw   = t / (68 * 8);
            int rem  = t % (68 * 8);
            int slot = rem >> 3;
            int kgc  = rem & 7;
            int arow = base_row + rw;
            f16x8 v = {};
            if (arow >= 0 && arow <= 60)
                v = *(const f16x8*)(actb + ((size_t)arow * 68 + slot) * 64 + kgc * 8);
            unsigned off = rw * 8704 + slot * 128 + ((kgc * 16) ^ ((slot & 7) << 4));
            *(f16x8*)(AS + off) = v;
        }
    }
    __syncthreads();

    int wave = __builtin_amdgcn_readfirstlane(tid >> 6);
    int pp   = wave >> 2;
    int qt   = wave & 3;
    int lane = tid & 63;
    int ml   = lane & 15;
    int kg   = lane >> 4;
    int q    = qt * 16 + ml;

    f32x4 acc = {0.f, 0.f, 0.f, 0.f};
#pragma unroll
    for (int ks = 0; ks < 32; ++ks) {
        int tap = ks >> 1, ii = tap >> 2, kk = tap & 3;
        int rw    = pp + ii;
        int chunk = (ks & 1) * 4 + kg;            // c0 = (ks&1)*32 + kg*8
        int slot  = q + 1 + kk;
        unsigned off = rw * 8704 + slot * 128 + ((chunk * 16) ^ ((slot & 7) << 4));
        f16x8 A = *(const f16x8*)(AS + off);
        f16x8 F = *(const f16x8*)(FS + (ks * 64 + lane) * 8);
        acc = __builtin_amdgcn_mfma_f32_16x16x32_f16(F, A, acc, 0, 0, 0);
    }

    int p = 2 * pg + pp;
    size_t rbase = ((size_t)b * 256 + 4 * p + kg) * 256;
    f32x4 iv = *(const f32x4*)(img + rbase + 4 * q);
    f16x4 ev = {(f16)(iv[0] - acc[0]), (f16)(iv[1] - acc[1]),
                (f16)(iv[2] - acc[2]), (f16)(iv[3] - acc[3])};
    *(f16x4*)(eh + rbase + 4 * q) = ev;
}

// ---------------------------------------------------------------------------
// gk (R12): conv(e,filt) + fused Adam.  SWAPPED mfma(B,A): D row = c-in-tile,
// col = j.  Per lane: j = jt*16+(lane&15), c = nt*16+(lane>>4)*4+rg.
// u/mv NHWC [b][i][j][64c] -> f32x4 / f16x8 fully-contiguous accesses;
// actc write = contiguous f16x4; out write = contiguous f32x4.
// MODE 0: first iter.  MODE 1: middle.  MODE 2: last -> NHWC out only.
// ---------------------------------------------------------------------------
template <int MODE>
__global__ __launch_bounds__(256) void gk(float* __restrict__ u,
                                          f16* __restrict__ mv,
                                          f16* __restrict__ actc,
                                          float* __restrict__ out,
                                          const f16* __restrict__ eh,
                                          const f16* __restrict__ Bf,
                                          float rbc1, float rbc2) {
    __shared__ f16 BS[8 * 4 * 64 * 8];            // 16 KB
    int tid = threadIdx.x;
    {
        const f32x4* s = (const f32x4*)Bf;
        f32x4* d = (f32x4*)BS;
        for (int idx = tid; idx < 1024; idx += 256) d[idx] = s[idx];
    }
    __syncthreads();

    int bid = blockIdx.x;                         // 1952 = 8 * 244
    int n   = (bid & 7) * 244 + (bid >> 3);
    int b   = n / 61;
    int i   = n % 61;
    int jt  = __builtin_amdgcn_readfirstlane(tid >> 6);
    int lane = tid & 63;
    int kg  = lane >> 4;
    int ml  = lane & 15;

    // A (2nd operand): lane&15 = j, k=(lane>>4)*8+e ; kh=2ks+(kg>>1), kw=(kg&1)*8+e
    const f16* ebase = eh + ((size_t)b * 256 + 4 * i) * 256
                     + 4 * (jt * 16 + ml) + (kg & 1) * 8;
    int khb = kg >> 1;

    f32x4 acc[4] = {{0.f,0.f,0.f,0.f}, {0.f,0.f,0.f,0.f},
                    {0.f,0.f,0.f,0.f}, {0.f,0.f,0.f,0.f}};
#pragma unroll
    for (int ks = 0; ks < 8; ++ks) {
        f16x8 A = *(const f16x8u*)(ebase + (2 * ks + khb) * 256);
#pragma unroll
        for (int nt = 0; nt < 4; ++nt) {
            f16x8 B = *(const f16x8*)(BS + ((ks * 4 + nt) * 64 + lane) * 8);
            acc[nt] = __builtin_amdgcn_mfma_f32_16x16x32_f16(B, A, acc[nt], 0, 0, 0);
        }
    }

    // D (swapped): col = lane&15 = j-in-tile ; row = (lane>>4)*4+rg = c-in-tile
    int j   = jt * 16 + ml;
    int jr  = (j <= 60) ? j : 60;                 // clamp (reads harmless)
    bool wok = (j <= 60);
    size_t pix = (size_t)(b * 61 + i) * 61 + jr;

#pragma unroll
    for (int nt = 0; nt < 4; ++nt) {
        int cc = nt * 16 + kg * 4;                // 4 consecutive c per lane
        size_t sbase = pix * 64 + cc;
        if (MODE == 0) {
            f32x4 u4;
            f16x8 mv8;
            f16x4 a4;
#pragma unroll
            for (int rg = 0; rg < 4; ++rg) {
                float g  = acc[nt][rg];
                float m2 = (1.f - B1F) * g;
                float v2 = (1.f - B2F) * g * g;
                u4[rg] = LRF * (m2 * rbc1) / (sqrtf(v2 * rbc2) + EPSF);
                mv8[2 * rg]     = (f16)m2;
                mv8[2 * rg + 1] = (f16)v2;
                a4[rg] = (f16)fmaxf(u4[rg] - LAMF, 0.f);
            }
            if (wok) {
                *(f32x4u*)(u + sbase) = u4;
                *(f16x8u*)(mv + 2 * sbase) = mv8;
                *(f16x4*)(actc + ((size_t)(b * 62 + i) * 68 + (j + 4)) * 64 + cc) = a4;
            }
        } else {
            f32x4 uu  = *(const f32x4u*)(u + sbase);
            f16x8 mv8 = *(const f16x8u*)(mv + 2 * sbase);
            float un[4];
#pragma unroll
            for (int rg = 0; rg < 4; ++rg) {
                float a  = fmaxf(uu[rg] - LAMF, 0.f);
                float g  = acc[nt][rg] + a - uu[rg];
                float m2 = B1F * (float)mv8[2 * rg]     + (1.f - B1F) * g;
                float v2 = B2F * (float)mv8[2 * rg + 1] + (1.f - B2F) * g * g;
                mv8[2 * rg]     = (f16)m2;
                mv8[2 * rg + 1] = (f16)v2;
                un[rg] = uu[rg] + LRF * (m2 * rbc1) / (sqrtf(v2 * rbc2) + EPSF);
            }
            if (MODE == 1) {
                if (wok) {
                    f32x4 u4 = {un[0], un[1], un[2], un[3]};
                    *(f32x4u*)(u + sbase) = u4;
                    *(f16x8u*)(mv + 2 * sbase) = mv8;
                    f16x4 a4 = {(f16)fmaxf(un[0] - LAMF, 0.f),
                                (f16)fmaxf(un[1] - LAMF, 0.f),
                                (f16)fmaxf(un[2] - LAMF, 0.f),
                                (f16)fmaxf(un[3] - LAMF, 0.f)};
                    *(f16x4*)(actc + ((size_t)(b * 62 + i) * 68 + (j + 4)) * 64 + cc) = a4;
                }
            } else {                              // MODE 2: output only
                if (wok) {
                    f32x4 o4 = {fmaxf(un[0] - LAMF, 0.f), fmaxf(un[1] - LAMF, 0.f),
                                fmaxf(un[2] - LAMF, 0.f), fmaxf(un[3] - LAMF, 0.f)};
                    *(f32x4u*)(out + pix * 64 + cc) = o4;
                }
            }
        }
    }
}

// ---------------------------------------------------------------------------
extern "C" void kernel_launch(void* const* d_in, const int* in_sizes, int n_in,
                              void* d_out, int out_size, void* d_ws, size_t ws_size,
                              hipStream_t stream) {
    const float* img  = (const float*)d_in[0];
    const float* filt = (const float*)d_in[1];
    float* out = (float*)d_out;

    float* u  = (float*)d_ws;
    f16* mv   = (f16*)(u + USZ);      // 2*USZ f16 interleaved (m,v), NHWC
    f16* eh   = mv + 2 * (size_t)USZ;
    f16* actc = eh + ESZ;
    f16* F2f  = actc + ACSZ;
    f16* Bf   = F2f + 16384;

    hipMemsetAsync(actc, 0, (size_t)ACSZ * sizeof(f16), stream);
    prep<<<128, 256, 0, stream>>>(filt, F2f, Bf);
    cvt<<<ESZ / 1024, 256, 0, stream>>>(img, eh);

    float b1p = B1F, b2p = B2F;
    gk<0><<<1952, 256, 0, stream>>>(u, mv, actc, out, eh, Bf,
                                    1.f / (1.f - b1p), 1.f / (1.f - b2p));
    for (int t = 1; t < 9; ++t) {
        b1p *= B1F;
        b2p *= B2F;
        ek<<<1024, 512, 0, stream>>>(actc, img, F2f, eh);
        gk<1><<<1952, 256, 0, stream>>>(u, mv, actc, out, eh, Bf,
                                        1.f / (1.f - b1p), 1.f / (1.f - b2p));
    }
    b1p *= B1F;
    b2p *= B2F;
    ek<<<1024, 512, 0, stream>>>(actc, img, F2f, eh);
    gk<2><<<1952, 256, 0, stream>>>(u, mv, actc, out, eh, Bf,
                                    1.f / (1.f - b1p), 1.f / (1.f - b2p));
}